// Round 1
// baseline (311.421 us; speedup 1.0000x reference)
//
#include <hip/hip_runtime.h>
#include <hip/hip_fp16.h>

#define N_PTS 100000
#define NB    32     // n
#define M_CL  16     // m
#define KNN   32     // k
#define MU_F  100.0f

typedef unsigned int uint;

// ---------------------------------------------------------------------------
// K1: encoded[row] = x . encoder_w[row,:] + b[row]
// grid = 32 rows x 8 chunks, block = 256. atomicAdd partials into enc (zeroed).
// ---------------------------------------------------------------------------
__global__ __launch_bounds__(256) void k_encode(const float* __restrict__ x,
                                                const float* __restrict__ W,
                                                const float* __restrict__ b,
                                                float* __restrict__ enc) {
    int row = blockIdx.x & 31;
    int chunk = blockIdx.x >> 5;         // 0..7
    const int CH = N_PTS / 8;            // 12500, divisible by 4
    int base = chunk * CH;
    const float4* W4 = reinterpret_cast<const float4*>(W + (size_t)row * N_PTS + base);
    const float4* x4 = reinterpret_cast<const float4*>(x + base);
    const int nv = CH / 4;               // 3125
    float acc = 0.f;
    for (int idx = threadIdx.x; idx < nv; idx += 256) {
        float4 w = W4[idx];
        float4 xv = x4[idx];
        acc += w.x * xv.x + w.y * xv.y + w.z * xv.z + w.w * xv.w;
    }
    #pragma unroll
    for (int off = 32; off > 0; off >>= 1) acc += __shfl_down(acc, off);
    __shared__ float sred[4];
    int wid = threadIdx.x >> 6;
    if ((threadIdx.x & 63) == 0) sred[wid] = acc;
    __syncthreads();
    if (threadIdx.x == 0) {
        float s = sred[0] + sred[1] + sred[2] + sred[3];
        if (chunk == 0) s += b[row];
        atomicAdd(enc + row, s);
    }
}

// ---------------------------------------------------------------------------
// K2: transpose decoder [32, N] f32 -> decT [N, 32] fp16 (64B rows)
// block = 256, tile = 32 rows x 64 cols
// ---------------------------------------------------------------------------
__global__ __launch_bounds__(256) void k_transpose(const float* __restrict__ dec,
                                                   __half* __restrict__ decT) {
    __shared__ float tile[32][65];
    int j0 = blockIdx.x * 64;
    int col = threadIdx.x & 63;
    int r0 = threadIdx.x >> 6;           // 0..3
    #pragma unroll
    for (int it = 0; it < 8; ++it) {
        int row = it * 4 + r0;
        int j = j0 + col;
        float v = (j < N_PTS) ? dec[(size_t)row * N_PTS + j] : 0.f;
        tile[row][col] = v;
    }
    __syncthreads();
    // write 64 j-rows x 16 half2 pairs = 1024 items, 4 iters
    #pragma unroll
    for (int it = 0; it < 4; ++it) {
        int idx = it * 256 + threadIdx.x;
        int j = idx >> 4;                // 0..63
        int p = idx & 15;                // i-pair
        int jj = j0 + j;
        if (jj < N_PTS) {
            __half2 h = __halves2half2(__float2half(tile[2 * p][j]),
                                       __float2half(tile[2 * p + 1][j]));
            *reinterpret_cast<__half2*>(decT + (size_t)jj * 32 + 2 * p) = h;
        }
    }
}

// ---------------------------------------------------------------------------
// device helper: compute inv[r] = 1/(sigmoid(enc.bw_w[r]+bw_b[r])*MU/60)^2
// ---------------------------------------------------------------------------
__device__ inline void build_inv(const float* __restrict__ encL,
                                 const float* __restrict__ bw_w,
                                 const float* __restrict__ bw_b,
                                 float* __restrict__ invL, int tid, int nthreads) {
    for (int r = tid; r < 512; r += nthreads) {
        float z = bw_b[r];
        const float* wr = bw_w + r * 32;
        #pragma unroll
        for (int p = 0; p < 32; ++p) z = fmaf(encL[p], wr[p], z);
        float s = 1.f / (1.f + __expf(-z));
        float wmu = s * (MU_F / 60.0f);
        invL[r] = 1.f / (wmu * wmu);
    }
}

// ---------------------------------------------------------------------------
// K3: S[i*32+kk] = sum_j relu(1 - d[j,kk]^2 * inv[i*16+label[j]])
// grid = 256 blocks x 1024 threads; thread = (i,kk); grid-stride over j.
// ---------------------------------------------------------------------------
__global__ __launch_bounds__(1024) void k_S(const float* __restrict__ enc_g,
                                            const float* __restrict__ bw_w,
                                            const float* __restrict__ bw_b,
                                            const float* __restrict__ nd,
                                            const int* __restrict__ labels,
                                            float* __restrict__ S) {
    __shared__ float invL[512];
    __shared__ float encL[32];
    if (threadIdx.x < 32) encL[threadIdx.x] = enc_g[threadIdx.x];
    __syncthreads();
    build_inv(encL, bw_w, bw_b, invL, threadIdx.x, 1024);
    __syncthreads();
    int i = threadIdx.x >> 5;
    int kk = threadIdx.x & 31;
    float acc = 0.f;
    for (int j = blockIdx.x; j < N_PTS; j += gridDim.x) {
        int lab = labels[j];
        float d = nd[(size_t)j * 32 + kk];
        float w = fmaf(-d * d, invL[i * 16 + lab], 1.0f);
        acc += fmaxf(w, 0.f);
    }
    atomicAdd(S + threadIdx.x, acc);
}

// ---------------------------------------------------------------------------
// K4 (main): out[j] = sum_kk sum_i E[i,kk] * win(i,j,kk) * decT[nid[j,kk], i]
//   E[i,kk] = enc[i]/S[i,kk]   (built per block in LDS)
// wave: lanes 0..31 -> j0 (kk=lane), lanes 32..63 -> j0+1
// ---------------------------------------------------------------------------
__global__ __launch_bounds__(256) void k_main(const float* __restrict__ enc_g,
                                              const float* __restrict__ bw_w,
                                              const float* __restrict__ bw_b,
                                              const float* __restrict__ S_g,
                                              const float* __restrict__ nd,
                                              const int* __restrict__ nid,
                                              const int* __restrict__ labels,
                                              const __half* __restrict__ decT,
                                              float* __restrict__ out) {
    __shared__ float invL[512];
    __shared__ float EL[1024];
    __shared__ float encL[32];
    if (threadIdx.x < 32) encL[threadIdx.x] = enc_g[threadIdx.x];
    __syncthreads();
    build_inv(encL, bw_w, bw_b, invL, threadIdx.x, 256);
    for (int t = threadIdx.x; t < 1024; t += 256) {
        EL[t] = encL[t >> 5] / S_g[t];
    }
    __syncthreads();

    int lane = threadIdx.x & 63;
    int kk = lane & 31;
    int jh = lane >> 5;
    int gwave = blockIdx.x * 4 + (threadIdx.x >> 6);
    int nwaves = gridDim.x * 4;

    float E_reg[32];
    #pragma unroll
    for (int i = 0; i < 32; ++i) E_reg[i] = EL[i * 32 + kk];

    for (int pair = gwave; pair < N_PTS / 2; pair += nwaves) {
        int j = pair * 2 + jh;
        int c = labels[j];
        float d = nd[(size_t)j * 32 + kk];
        float d2 = d * d;
        int id = nid[(size_t)j * 32 + kk];
        const uint4* rp = reinterpret_cast<const uint4*>(decT + (size_t)id * 32);
        uint4 q0 = rp[0], q1 = rp[1], q2 = rp[2], q3 = rp[3];
        uint dvs[16] = {q0.x, q0.y, q0.z, q0.w,
                        q1.x, q1.y, q1.z, q1.w,
                        q2.x, q2.y, q2.z, q2.w,
                        q3.x, q3.y, q3.z, q3.w};
        float acc = 0.f;
        #pragma unroll
        for (int p = 0; p < 16; ++p) {
            float2 f = __half22float2(*reinterpret_cast<const __half2*>(&dvs[p]));
            int i0 = 2 * p, i1 = 2 * p + 1;
            float w0 = fmaxf(fmaf(-d2, invL[i0 * 16 + c], 1.f), 0.f);
            float w1 = fmaxf(fmaf(-d2, invL[i1 * 16 + c], 1.f), 0.f);
            acc = fmaf(w0 * E_reg[i0], f.x, acc);
            acc = fmaf(w1 * E_reg[i1], f.y, acc);
        }
        #pragma unroll
        for (int off = 16; off > 0; off >>= 1) acc += __shfl_xor(acc, off);
        if (kk == 0) out[j] = acc;
    }
}

// ---------------------------------------------------------------------------
extern "C" void kernel_launch(void* const* d_in, const int* in_sizes, int n_in,
                              void* d_out, int out_size, void* d_ws, size_t ws_size,
                              hipStream_t stream) {
    const float* x     = (const float*)d_in[0];
    const float* enc_w = (const float*)d_in[1];
    const float* enc_b = (const float*)d_in[2];
    const float* dec   = (const float*)d_in[3];
    const float* bw_w  = (const float*)d_in[4];
    const float* bw_b  = (const float*)d_in[5];
    const float* nd    = (const float*)d_in[6];
    const int*   nid   = (const int*)d_in[7];
    const int*   labels= (const int*)d_in[8];
    float* out = (float*)d_out;

    // ws layout: [0,32) enc | [32,1056) S | byte 16384: decT (N*32 fp16, 6.4MB)
    float* enc = (float*)d_ws;
    float* S   = enc + 32;
    __half* decT = (__half*)((char*)d_ws + 16384);

    hipMemsetAsync(d_ws, 0, 16384, stream);                       // zero enc + S
    k_encode<<<dim3(256), dim3(256), 0, stream>>>(x, enc_w, enc_b, enc);
    k_transpose<<<dim3((N_PTS + 63) / 64), dim3(256), 0, stream>>>(dec, decT);
    k_S<<<dim3(256), dim3(1024), 0, stream>>>(enc, bw_w, bw_b, nd, labels, S);
    k_main<<<dim3(2048), dim3(256), 0, stream>>>(enc, bw_w, bw_b, S, nd, nid,
                                                 labels, decT, out);
}

// Round 2
// 215.947 us; speedup vs baseline: 1.4421x; 1.4421x over previous
//
#include <hip/hip_runtime.h>
#include <hip/hip_fp16.h>

#define N_PTS 100000
#define MU_F  100.0f

typedef unsigned int uint;

// ---------------------------------------------------------------------------
// K1: encoded[row] = x . encoder_w[row,:] + b[row]
// grid = 32 rows x 8 chunks, block = 256. atomicAdd partials into enc (zeroed).
// ---------------------------------------------------------------------------
__global__ __launch_bounds__(256) void k_encode(const float* __restrict__ x,
                                                const float* __restrict__ W,
                                                const float* __restrict__ b,
                                                float* __restrict__ enc) {
    int row = blockIdx.x & 31;
    int chunk = blockIdx.x >> 5;         // 0..7
    const int CH = N_PTS / 8;            // 12500, divisible by 4
    int base = chunk * CH;
    const float4* W4 = reinterpret_cast<const float4*>(W + (size_t)row * N_PTS + base);
    const float4* x4 = reinterpret_cast<const float4*>(x + base);
    const int nv = CH / 4;               // 3125
    float acc = 0.f;
    for (int idx = threadIdx.x; idx < nv; idx += 256) {
        float4 w = W4[idx];
        float4 xv = x4[idx];
        acc += w.x * xv.x + w.y * xv.y + w.z * xv.z + w.w * xv.w;
    }
    #pragma unroll
    for (int off = 32; off > 0; off >>= 1) acc += __shfl_down(acc, off);
    __shared__ float sred[4];
    int wid = threadIdx.x >> 6;
    if ((threadIdx.x & 63) == 0) sred[wid] = acc;
    __syncthreads();
    if (threadIdx.x == 0) {
        float s = sred[0] + sred[1] + sred[2] + sred[3];
        if (chunk == 0) s += b[row];
        atomicAdd(enc + row, s);
    }
}

// ---------------------------------------------------------------------------
// K2: transpose decoder [32, N] f32 -> decT [N, 32] fp16 (64B rows)
// ---------------------------------------------------------------------------
__global__ __launch_bounds__(256) void k_transpose(const float* __restrict__ dec,
                                                   __half* __restrict__ decT) {
    __shared__ float tile[32][65];
    int j0 = blockIdx.x * 64;
    int col = threadIdx.x & 63;
    int r0 = threadIdx.x >> 6;           // 0..3
    #pragma unroll
    for (int it = 0; it < 8; ++it) {
        int row = it * 4 + r0;
        int j = j0 + col;
        float v = (j < N_PTS) ? dec[(size_t)row * N_PTS + j] : 0.f;
        tile[row][col] = v;
    }
    __syncthreads();
    #pragma unroll
    for (int it = 0; it < 4; ++it) {
        int idx = it * 256 + threadIdx.x;
        int j = idx >> 4;                // 0..63
        int p = idx & 15;                // i-pair
        int jj = j0 + j;
        if (jj < N_PTS) {
            __half2 h = __halves2half2(__float2half(tile[2 * p][j]),
                                       __float2half(tile[2 * p + 1][j]));
            *reinterpret_cast<__half2*>(decT + (size_t)jj * 32 + 2 * p) = h;
        }
    }
}

// ---------------------------------------------------------------------------
// K3a: global histogram of labels (16 bins)
// ---------------------------------------------------------------------------
__global__ __launch_bounds__(256) void k_hist(const int* __restrict__ labels,
                                              int* __restrict__ ghist) {
    __shared__ int lh[16];
    if (threadIdx.x < 16) lh[threadIdx.x] = 0;
    __syncthreads();
    for (int j = blockIdx.x * 256 + threadIdx.x; j < N_PTS; j += gridDim.x * 256)
        atomicAdd(&lh[labels[j]], 1);
    __syncthreads();
    if (threadIdx.x < 16) atomicAdd(&ghist[threadIdx.x], lh[threadIdx.x]);
}

// ---------------------------------------------------------------------------
// K3b: exclusive scan of 16 bins -> base; init cursor
// ---------------------------------------------------------------------------
__global__ void k_scan(const int* __restrict__ ghist,
                       int* __restrict__ gbase, int* __restrict__ gcursor) {
    if (threadIdx.x == 0) {
        int run = 0;
        for (int c = 0; c < 16; ++c) {
            gbase[c] = run;
            gcursor[c] = run;
            run += ghist[c];
        }
    }
}

// ---------------------------------------------------------------------------
// K3c: counting-sort scatter: perm[pos] = j, grouped by cluster
// grid = 128 blocks, each takes a contiguous chunk of 784 js
// ---------------------------------------------------------------------------
__global__ __launch_bounds__(256) void k_scatter(const int* __restrict__ labels,
                                                 int* __restrict__ gcursor,
                                                 int* __restrict__ perm) {
    __shared__ int lh[16], lbase[16], lcur[16];
    const int CHUNK = 784;               // 128 * 784 >= 100000
    int start = blockIdx.x * CHUNK;
    int end = min(start + CHUNK, N_PTS);
    if (threadIdx.x < 16) { lh[threadIdx.x] = 0; lcur[threadIdx.x] = 0; }
    __syncthreads();
    for (int j = start + threadIdx.x; j < end; j += 256)
        atomicAdd(&lh[labels[j]], 1);
    __syncthreads();
    if (threadIdx.x < 16)
        lbase[threadIdx.x] = atomicAdd(&gcursor[threadIdx.x], lh[threadIdx.x]);
    __syncthreads();
    for (int j = start + threadIdx.x; j < end; j += 256) {
        int c = labels[j];
        int lpos = atomicAdd(&lcur[c], 1);
        perm[lbase[c] + lpos] = j;
    }
}

// ---------------------------------------------------------------------------
// helper: thread i<32 computes inv[i*16+c] for the block's cluster c
// ---------------------------------------------------------------------------
__device__ inline void build_invC(const float* __restrict__ encL,
                                  const float* __restrict__ bw_w,
                                  const float* __restrict__ bw_b,
                                  float* __restrict__ invCL, int c) {
    if (threadIdx.x < 32) {
        int r = threadIdx.x * 16 + c;
        float z = bw_b[r];
        const float* wr = bw_w + r * 32;
        #pragma unroll
        for (int p = 0; p < 32; ++p) z = fmaf(encL[p], wr[p], z);
        float s = 1.f / (1.f + __expf(-z));
        float wmu = s * (MU_F / 60.0f);
        invCL[threadIdx.x] = 1.f / (wmu * wmu);
    }
}

// ---------------------------------------------------------------------------
// K4: S[i*32+kk] = sum_j relu(1 - d^2 * inv[i,label]) via sorted traversal
// block: cluster c = blockIdx&15, chunk = blockIdx>>4. lane=(jh,kk), acc[32].
// ---------------------------------------------------------------------------
__global__ __launch_bounds__(256, 4) void k_S_sorted(const float* __restrict__ enc_g,
                                                     const float* __restrict__ bw_w,
                                                     const float* __restrict__ bw_b,
                                                     const float* __restrict__ nd,
                                                     const int* __restrict__ perm,
                                                     const int* __restrict__ gbase,
                                                     const int* __restrict__ ghist,
                                                     float* __restrict__ S) {
    __shared__ float encL[32], invCL[32];
    __shared__ float Sloc[1024];
    int c = blockIdx.x & 15;
    int chunk = blockIdx.x >> 4;
    int nch = gridDim.x >> 4;
    if (threadIdx.x < 32) encL[threadIdx.x] = enc_g[threadIdx.x];
    for (int t = threadIdx.x; t < 1024; t += 256) Sloc[t] = 0.f;
    __syncthreads();
    build_invC(encL, bw_w, bw_b, invCL, c);
    __syncthreads();

    float invC[32];
    #pragma unroll
    for (int i = 0; i < 32; ++i) invC[i] = invCL[i];

    int cnt = ghist[c];
    int bs = gbase[c];
    if (cnt > 0) {
        int lane = threadIdx.x & 63;
        int kk = lane & 31;
        int jh = lane >> 5;
        int gw = chunk * 4 + (threadIdx.x >> 6);
        int nw = nch * 4;
        int npairs = (cnt + 1) >> 1;

        float acc[32];
        #pragma unroll
        for (int i = 0; i < 32; ++i) acc[i] = 0.f;

        for (int pp = gw; pp < npairs; pp += nw) {
            int p = bs + 2 * pp + jh;
            bool valid = p < bs + cnt;
            int j = perm[valid ? p : bs];
            float d = nd[(size_t)j * 32 + kk];
            float d2 = valid ? d * d : 1e30f;
            #pragma unroll
            for (int i = 0; i < 32; ++i)
                acc[i] += fmaxf(fmaf(-d2, invC[i], 1.0f), 0.f);
        }
        #pragma unroll
        for (int i = 0; i < 32; ++i)
            atomicAdd(&Sloc[i * 32 + kk], acc[i]);
    }
    __syncthreads();
    for (int t = threadIdx.x; t < 1024; t += 256)
        if (Sloc[t] != 0.f) atomicAdd(S + t, Sloc[t]);
}

// ---------------------------------------------------------------------------
// K5 (main): out[j] = sum_kk sum_i E[i,kk]*relu(1-d2*invC[i])*decT[nid[j,kk],i]
// sorted traversal: c uniform per block -> invC in registers, no LDS in loop.
// ---------------------------------------------------------------------------
__global__ __launch_bounds__(256, 4) void k_main(const float* __restrict__ enc_g,
                                                 const float* __restrict__ bw_w,
                                                 const float* __restrict__ bw_b,
                                                 const float* __restrict__ S_g,
                                                 const float* __restrict__ nd,
                                                 const int* __restrict__ nid,
                                                 const int* __restrict__ perm,
                                                 const int* __restrict__ gbase,
                                                 const int* __restrict__ ghist,
                                                 const __half* __restrict__ decT,
                                                 float* __restrict__ out) {
    __shared__ float encL[32], invCL[32];
    int c = blockIdx.x & 15;
    int chunk = blockIdx.x >> 4;
    int nch = gridDim.x >> 4;
    if (threadIdx.x < 32) encL[threadIdx.x] = enc_g[threadIdx.x];
    __syncthreads();
    build_invC(encL, bw_w, bw_b, invCL, c);
    __syncthreads();

    int lane = threadIdx.x & 63;
    int kk = lane & 31;
    int jh = lane >> 5;
    int gw = chunk * 4 + (threadIdx.x >> 6);
    int nw = nch * 4;

    float invC[32], E_reg[32];
    #pragma unroll
    for (int i = 0; i < 32; ++i) {
        invC[i] = invCL[i];
        E_reg[i] = encL[i] / S_g[i * 32 + kk];
    }

    int cnt = ghist[c];
    int bs = gbase[c];
    if (cnt == 0) return;
    int npairs = (cnt + 1) >> 1;

    for (int pp = gw; pp < npairs; pp += nw) {
        int p = bs + 2 * pp + jh;
        bool valid = p < bs + cnt;
        int j = perm[valid ? p : bs];
        float d = nd[(size_t)j * 32 + kk];
        float d2 = d * d;
        int id = nid[(size_t)j * 32 + kk];
        const uint4* rp = reinterpret_cast<const uint4*>(decT + (size_t)id * 32);
        uint4 q0 = rp[0], q1 = rp[1], q2 = rp[2], q3 = rp[3];
        uint dvs[16] = {q0.x, q0.y, q0.z, q0.w,
                        q1.x, q1.y, q1.z, q1.w,
                        q2.x, q2.y, q2.z, q2.w,
                        q3.x, q3.y, q3.z, q3.w};
        float acc = 0.f;
        #pragma unroll
        for (int p2 = 0; p2 < 16; ++p2) {
            float2 f = __half22float2(*reinterpret_cast<const __half2*>(&dvs[p2]));
            int i0 = 2 * p2, i1 = 2 * p2 + 1;
            float w0 = fmaxf(fmaf(-d2, invC[i0], 1.f), 0.f);
            float w1 = fmaxf(fmaf(-d2, invC[i1], 1.f), 0.f);
            acc = fmaf(w0 * E_reg[i0], f.x, acc);
            acc = fmaf(w1 * E_reg[i1], f.y, acc);
        }
        #pragma unroll
        for (int off = 16; off > 0; off >>= 1) acc += __shfl_xor(acc, off);
        if (kk == 0 && valid) out[j] = acc;
    }
}

// ---------------------------------------------------------------------------
extern "C" void kernel_launch(void* const* d_in, const int* in_sizes, int n_in,
                              void* d_out, int out_size, void* d_ws, size_t ws_size,
                              hipStream_t stream) {
    const float* x     = (const float*)d_in[0];
    const float* enc_w = (const float*)d_in[1];
    const float* enc_b = (const float*)d_in[2];
    const float* dec   = (const float*)d_in[3];
    const float* bw_w  = (const float*)d_in[4];
    const float* bw_b  = (const float*)d_in[5];
    const float* nd    = (const float*)d_in[6];
    const int*   nid   = (const int*)d_in[7];
    const int*   labels= (const int*)d_in[8];
    float* out = (float*)d_out;

    // ws layout:
    //   [0,128)        enc (32 f)
    //   [128,4224)     S (1024 f)
    //   [4224,4288)    ghist (16 i)
    //   [4288,4352)    gbase (16 i)
    //   [4352,4416)    gcursor (16 i)
    //   [8192,408192)  perm (100000 i)
    //   [409600,...)   decT (N*32 fp16, 6.4 MB)
    char* ws = (char*)d_ws;
    float* enc    = (float*)(ws + 0);
    float* S      = (float*)(ws + 128);
    int* ghist    = (int*)(ws + 4224);
    int* gbase    = (int*)(ws + 4288);
    int* gcursor  = (int*)(ws + 4352);
    int* perm     = (int*)(ws + 8192);
    __half* decT  = (__half*)(ws + 409600);

    hipMemsetAsync(d_ws, 0, 8192, stream);   // zero enc, S, ghist
    k_encode<<<dim3(256), dim3(256), 0, stream>>>(x, enc_w, enc_b, enc);
    k_transpose<<<dim3((N_PTS + 63) / 64), dim3(256), 0, stream>>>(dec, decT);
    k_hist<<<dim3(64), dim3(256), 0, stream>>>(labels, ghist);
    k_scan<<<dim3(1), dim3(64), 0, stream>>>(ghist, gbase, gcursor);
    k_scatter<<<dim3(128), dim3(256), 0, stream>>>(labels, gcursor, perm);
    k_S_sorted<<<dim3(256), dim3(256), 0, stream>>>(enc, bw_w, bw_b, nd, perm,
                                                    gbase, ghist, S);
    k_main<<<dim3(2048), dim3(256), 0, stream>>>(enc, bw_w, bw_b, S, nd, nid,
                                                 perm, gbase, ghist, decT, out);
}